// Round 1
// baseline (144.912 us; speedup 1.0000x reference)
//
#include <hip/hip_runtime.h>

// Problem constants (from reference)
#define BB     32
#define C_IN   64
#define HH     64
#define WW     64
#define C_OUT  128
#define CONN   4     // 1 << TREE_DEPTH
// PADDING=2 -> pad_l = pad_r = 1, edge mode -> clamp coords to [0, 63]

__global__ __launch_bounds__(256) void lp_conv_bt_kernel(
    const float* __restrict__ x,       // (B, C_IN, H, W)
    const float* __restrict__ weights, // (C_OUT, CONN)
    const float* __restrict__ bias,    // (C_OUT)
    const int*   __restrict__ conn,    // (C_OUT, CONN), values in [0, C_IN*9)
    float*       __restrict__ out)     // (B, C_OUT, H, W)
{
    // Each thread computes 4 consecutive j's (float4 store).
    // vid bits: [3:0]=j4 (W/4=16), [9:4]=i, [16:10]=o, [21:17]=b
    int vid = blockIdx.x * blockDim.x + threadIdx.x;
    int j0 = (vid & 15) << 2;
    int i  = (vid >> 4) & 63;
    int o  = (vid >> 10) & 127;
    int b  = vid >> 17;

    const float* xb = x + (size_t)b * (C_IN * HH * WW);

    float acc0 = 0.f, acc1 = 0.f, acc2 = 0.f, acc3 = 0.f;

#pragma unroll
    for (int k = 0; k < CONN; ++k) {
        int   ci = conn[o * CONN + k];
        float wk = weights[o * CONN + k];
        int c   = ci / 9;
        int rem = ci - c * 9;
        int di  = rem / 3;
        int dj  = rem - di * 3;

        int hh = i + di - 1;
        hh = hh < 0 ? 0 : (hh > HH - 1 ? HH - 1 : hh);
        const float* px = xb + (c * HH + hh) * WW;

        int w0 = j0 + dj - 1;                 // unpadded col of first lane elem
        int ww0 = min(max(w0,     0), WW - 1);
        int ww1 = min(max(w0 + 1, 0), WW - 1);
        int ww2 = min(max(w0 + 2, 0), WW - 1);
        int ww3 = min(max(w0 + 3, 0), WW - 1);

        acc0 = fmaxf(acc0, fabsf(wk - px[ww0]));
        acc1 = fmaxf(acc1, fabsf(wk - px[ww1]));
        acc2 = fmaxf(acc2, fabsf(wk - px[ww2]));
        acc3 = fmaxf(acc3, fabsf(wk - px[ww3]));
    }

    float bo = bias[o];
    float4 r = make_float4(acc0 + bo, acc1 + bo, acc2 + bo, acc3 + bo);
    *reinterpret_cast<float4*>(out + (size_t)vid * 4) = r;
}

extern "C" void kernel_launch(void* const* d_in, const int* in_sizes, int n_in,
                              void* d_out, int out_size, void* d_ws, size_t ws_size,
                              hipStream_t stream) {
    const float* x       = (const float*)d_in[0];
    const float* weights = (const float*)d_in[1];
    const float* bias    = (const float*)d_in[2];
    const int*   conn    = (const int*)d_in[3];
    float*       out     = (float*)d_out;

    int total_vec = BB * C_OUT * HH * WW / 4;   // 4,194,304
    int block = 256;
    int grid  = total_vec / block;              // 16,384
    lp_conv_bt_kernel<<<grid, block, 0, stream>>>(x, weights, bias, conn, out);
}

// Round 2
// 107.297 us; speedup vs baseline: 1.3506x; 1.3506x over previous
//
#include <hip/hip_runtime.h>

// Problem constants (from reference)
#define BB     32
#define C_IN   64
#define HH     64
#define WW     64
#define C_OUT  128
#define CONN   4     // 1 << TREE_DEPTH
// PADDING=2 -> pad_l = pad_r = 1, "edge" mode -> clamp coords to [0, 63]

// Mapping:
//  - lane (0..63)  = output column j          -> every x load is 64 consecutive
//                                               floats (fully coalesced)
//  - each thread handles 8 consecutive output rows i0..i0+7
//  - block = 256 threads = 4 waves; each wave owns one 8-row chunk
//  - blockIdx bits: [0]=which 32-row half, [7:1]=o, [12:8]=b
//  - o is block-uniform -> conn/weights/bias loads scalarize (s_load);
//    i0 forced wave-uniform via readfirstlane -> row addressing is SALU,
//    inner loop is just v_sub + v_max(|.|) per element.
__global__ __launch_bounds__(256) void lp_conv_bt_kernel(
    const float* __restrict__ x,       // (B, C_IN, H, W)
    const float* __restrict__ weights, // (C_OUT, CONN)
    const float* __restrict__ bias,    // (C_OUT)
    const int*   __restrict__ conn,    // (C_OUT, CONN)
    float*       __restrict__ out)     // (B, C_OUT, H, W)
{
    const int bid   = blockIdx.x;
    const int b     = bid >> 8;
    const int o     = (bid >> 1) & (C_OUT - 1);
    const int ihalf = bid & 1;

    const int tid  = threadIdx.x;
    const int lane = tid & 63;
    int i0 = ihalf * 32 + (tid >> 6) * 8;
    i0 = __builtin_amdgcn_readfirstlane(i0);   // wave-uniform -> SALU addressing

    float acc[8];
#pragma unroll
    for (int i = 0; i < 8; ++i) acc[i] = 0.f;

#pragma unroll
    for (int k = 0; k < CONN; ++k) {
        const int   ci = conn[o * CONN + k];   // uniform -> s_load
        const float wk = weights[o * CONN + k];
        int c   = ci / 9;
        int rem = ci - c * 9;
        int di  = rem / 3;
        int dj  = rem - di * 3;

        // per-lane column (only per-lane VALU in this k): clamp(j + dj - 1)
        int col = lane + dj - 1;
        col = min(max(col, 0), WW - 1);

        const float* base = x + (((size_t)b * C_IN + c) << 12);  // channel base

#pragma unroll
        for (int i = 0; i < 8; ++i) {
            int hh = i0 + i + di - 1;                 // wave-uniform row
            hh = min(max(hh, 0), HH - 1);
            float v = base[(hh << 6) + col];
            acc[i] = fmaxf(acc[i], fabsf(wk - v));
        }
    }

    const float bo = bias[o];
    float* po = out + (((size_t)(b * C_OUT + o) * HH + i0) << 6) + lane;
#pragma unroll
    for (int i = 0; i < 8; ++i)
        po[i << 6] = acc[i] + bo;
}

extern "C" void kernel_launch(void* const* d_in, const int* in_sizes, int n_in,
                              void* d_out, int out_size, void* d_ws, size_t ws_size,
                              hipStream_t stream) {
    const float* x       = (const float*)d_in[0];
    const float* weights = (const float*)d_in[1];
    const float* bias    = (const float*)d_in[2];
    const int*   conn    = (const int*)d_in[3];
    float*       out     = (float*)d_out;

    int grid = BB * C_OUT * 2;   // 8192 blocks of 256 threads
    lp_conv_bt_kernel<<<grid, 256, 0, stream>>>(x, weights, bias, conn, out);
}